// Round 1
// baseline (586.669 us; speedup 1.0000x reference)
//
#include <hip/hip_runtime.h>
#include <math.h>

// Problem constants (fixed by the reference setup_inputs)
#define BB 4
#define CC 256
#define HH 64
#define WW 64
#define PP 256
#define NPT 9      // 3x3 sampling points
#define NPIX 16384 // B*H*W

// Workspace layout (float element offsets)
#define WS_OFF   0ull                         // [B][27][H][W]       = 442368
#define WS_Y     442368ull                    // [B][P][H][W]        = 4194304
#define WS_SUM   4636672ull                   // [256]
#define WS_SUMSQ 4636928ull                   // [256]
#define WS_SCALE 4637184ull                   // [256]
#define WS_SHIFT 4637440ull                   // [256]
#define WS_WT    4637696ull                   // [c][k][oc] 256*9*256 = 589824
#define WS_WPMT  5227520ull                   // [c][j][27] 256*9*27  = 62208
// total 5289728 floats = 21.2 MB

// ---------------------------------------------------------------------------
// K0: weight relayout + zero BN accumulators (re-done every call; ws is
// poisoned 0xAA before each timed launch).
// ---------------------------------------------------------------------------
__global__ void k_transpose(const float* __restrict__ w,
                            const float* __restrict__ w_p,
                            const float* __restrict__ w_m,
                            float* __restrict__ ws) {
  float* wT   = ws + WS_WT;
  float* wPMt = ws + WS_WPMT;
  int idx = blockIdx.x * 256 + threadIdx.x;

  if (blockIdx.x == 0 && threadIdx.x < 512) {
    ws[WS_SUM + threadIdx.x] = 0.f;  // covers SUM[256] + SUMSQ[256]
  }

  // main weight: [oc][c][k] -> [c][k][oc]
  for (int i = idx; i < 256 * 256 * 9; i += gridDim.x * 256) {
    int oc = i % 256;
    int r  = i / 256;
    int k  = r % 9;
    int c  = r / 9;
    wT[i] = w[((size_t)oc * CC + c) * 9 + k];
  }
  // offset+mask weights fused: [c][j][oc27]
  for (int i = idx; i < 256 * 9 * 27; i += gridDim.x * 256) {
    int oc = i % 27;
    int r  = i / 27;
    int j  = r % 9;
    int c  = r / 9;
    wPMt[i] = (oc < 18) ? w_p[((size_t)oc * CC + c) * 9 + j]
                        : w_m[((size_t)(oc - 18) * CC + c) * 9 + j];
  }
}

// ---------------------------------------------------------------------------
// K1: fused offset (18ch) + mask (9ch, sigmoid) 3x3 conv, padding=1.
// grid = B*H (256), block = 512 (8 c-chunks x 64 w). LDS reduce over chunks.
// ---------------------------------------------------------------------------
__global__ __launch_bounds__(512) void k_offmask(const float* __restrict__ x,
                                                 const float* __restrict__ b_p,
                                                 const float* __restrict__ b_m,
                                                 float* __restrict__ ws) {
  const float* wPMt = ws + WS_WPMT;
  float* offm = ws + WS_OFF;

  __shared__ float sAcc[27 * 512];

  int t = threadIdx.x;
  int w = t & 63;
  int chunk = __builtin_amdgcn_readfirstlane(t >> 6);  // wave-uniform
  int blk = blockIdx.x;
  int b = blk >> 6, h = blk & 63;

  float acc[27];
#pragma unroll
  for (int j = 0; j < 27; ++j) acc[j] = 0.f;

  const float* xb = x + (size_t)b * CC * HH * WW;

  for (int ci = 0; ci < 32; ++ci) {
    int c = chunk * 32 + ci;
    const float* xp = xb + (size_t)c * HH * WW;
    float xv[9];
#pragma unroll
    for (int dh = -1; dh <= 1; ++dh) {
#pragma unroll
      for (int dw = -1; dw <= 1; ++dw) {
        int hh = h + dh, wv = w + dw;
        float v = 0.f;
        if ((unsigned)hh < 64u && (unsigned)wv < 64u) v = xp[hh * 64 + wv];
        xv[(dh + 1) * 3 + (dw + 1)] = v;
      }
    }
    const float* wb = wPMt + (size_t)c * 9 * 27;
#pragma unroll
    for (int j = 0; j < 9; ++j) {
#pragma unroll
      for (int oc = 0; oc < 27; ++oc)
        acc[oc] = fmaf(xv[j], wb[j * 27 + oc], acc[oc]);
    }
  }

#pragma unroll
  for (int j = 0; j < 27; ++j) sAcc[j * 512 + t] = acc[j];
  __syncthreads();

  for (int oi = t; oi < 27 * 64; oi += 512) {
    int oc = oi >> 6, wv = oi & 63;
    float s = 0.f;
#pragma unroll
    for (int ch = 0; ch < 8; ++ch) s += sAcc[oc * 512 + ch * 64 + wv];
    s += (oc < 18) ? b_p[oc] : b_m[oc - 18];
    if (oc >= 18) s = 1.f / (1.f + expf(-s));  // sigmoid for mask channels
    offm[(((size_t)b * 27 + oc) * 64 + h) * 64 + wv] = s;
  }
}

// ---------------------------------------------------------------------------
// K2: deformable gather + main contraction + BN partial sums.
// grid = B*H (256 blocks), block = 1024.
// Phase A: positions & bilinear*mask weights for 64 pixels x 9 pts -> LDS.
// K-loop: stage x_off[4c][9k][64w] in LDS, each thread (oc = t&255,
//         q4 = t>>8) accumulates 16 pixels for its output channel.
// ---------------------------------------------------------------------------
__global__ __launch_bounds__(1024) void k_deform(const float* __restrict__ x,
                                                 float* __restrict__ ws) {
  const float* offm = ws + WS_OFF;
  const float* wT   = ws + WS_WT;
  float* y     = ws + WS_Y;
  float* gsum  = ws + WS_SUM;
  float* gsum2 = ws + WS_SUMSQ;

  __shared__ __align__(16) int   sQ[4][576];   // qx0,qx1,qy0,qy1 (unpadded coords)
  __shared__ __align__(16) float sG[4][576];   // bilinear weights * mask
  __shared__ __align__(16) float sX[4][576];   // staged x_off tile
  __shared__ __align__(16) float sRed[2048];

  int t = threadIdx.x;
  int blk = blockIdx.x;
  int b = blk >> 6, h = blk & 63;

  if (t < 576) {
    int k = t / 64, w = t & 63;
    size_t base = (((size_t)b * 27) * 64 + h) * 64 + w;
    float offx = offm[base + (size_t)k * 4096];
    float offy = offm[base + (size_t)(9 + k) * 4096];
    float mk   = offm[base + (size_t)(18 + k) * 4096];
    float pnx = (float)((k / 3 - 1) * 6);
    float pny = (float)((k % 3 - 1) * 6);
    float px = (float)(h + 1) + pnx + offx;
    float py = (float)(w + 1) + pny + offy;
    float fx = floorf(px), fy = floorf(py);
    float q0x = fminf(fmaxf(fx, 0.f), 75.f);
    float q1x = fminf(fmaxf(fx + 1.f, 0.f), 75.f);
    float q0y = fminf(fmaxf(fy, 0.f), 75.f);
    float q1y = fminf(fmaxf(fy + 1.f, 0.f), 75.f);
    float pxc = fminf(fmaxf(px, 0.f), 75.f);
    float pyc = fminf(fmaxf(py, 0.f), 75.f);
    // deform-conv-v2 weights (exact reference formulation, clipped coords)
    float glt = (1.f + (q0x - pxc)) * (1.f + (q0y - pyc));
    float grb = (1.f - (q1x - pxc)) * (1.f - (q1y - pyc));
    float glb = (1.f + (q0x - pxc)) * (1.f - (q1y - pyc));
    float grt = (1.f - (q1x - pxc)) * (1.f + (q0y - pyc));
    sQ[0][t] = (int)q0x - 6;  // to unpadded coords; OOB => tap = 0
    sQ[1][t] = (int)q1x - 6;
    sQ[2][t] = (int)q0y - 6;
    sQ[3][t] = (int)q1y - 6;
    sG[0][t] = glt * mk;
    sG[1][t] = grb * mk;
    sG[2][t] = glb * mk;
    sG[3][t] = grt * mk;
  }
  __syncthreads();

  int oc = t & 255;
  int q4 = t >> 8;  // wave-uniform (waves are 64-aligned)
  float acc[16];
#pragma unroll
  for (int i = 0; i < 16; ++i) acc[i] = 0.f;

  const float* xb = x + (size_t)b * CC * 4096;

  for (int c0 = 0; c0 < CC; c0 += 4) {
    __syncthreads();  // protect sX against previous iteration's readers
    for (int v = t; v < 4 * 576; v += 1024) {
      int cc = v / 576, r = v % 576;
      const float* xp = xb + (size_t)(c0 + cc) * 4096;
      int qx0 = sQ[0][r], qx1 = sQ[1][r], qy0 = sQ[2][r], qy1 = sQ[3][r];
      float v00 = ((unsigned)qx0 < 64u && (unsigned)qy0 < 64u) ? xp[qx0 * 64 + qy0] : 0.f;
      float v11 = ((unsigned)qx1 < 64u && (unsigned)qy1 < 64u) ? xp[qx1 * 64 + qy1] : 0.f;
      float v01 = ((unsigned)qx0 < 64u && (unsigned)qy1 < 64u) ? xp[qx0 * 64 + qy1] : 0.f;
      float v10 = ((unsigned)qx1 < 64u && (unsigned)qy0 < 64u) ? xp[qx1 * 64 + qy0] : 0.f;
      sX[cc][r] = sG[0][r] * v00 + sG[1][r] * v11 + sG[2][r] * v01 + sG[3][r] * v10;
    }
    __syncthreads();
#pragma unroll
    for (int cc = 0; cc < 4; ++cc) {
#pragma unroll
      for (int k = 0; k < 9; ++k) {
        float wt = wT[(((size_t)(c0 + cc) * 9) + k) * 256 + oc];
        const float* xo = &sX[cc][k * 64 + q4 * 16];
#pragma unroll
        for (int i = 0; i < 16; ++i) acc[i] = fmaf(xo[i], wt, acc[i]);
      }
    }
  }

  // epilogue: write y + BN partial sums
  float s = 0.f, s2 = 0.f;
  float* yp = y + ((((size_t)b * PP + oc) * 64 + h) * 64 + q4 * 16);
#pragma unroll
  for (int i = 0; i < 16; ++i) {
    yp[i] = acc[i];
    s += acc[i];
    s2 = fmaf(acc[i], acc[i], s2);
  }
  sRed[t] = s;
  sRed[1024 + t] = s2;
  __syncthreads();
  if (t < 256) {
    float a  = sRed[t] + sRed[t + 256] + sRed[t + 512] + sRed[t + 768];
    float a2 = sRed[1024 + t] + sRed[1024 + t + 256] + sRed[1024 + t + 512] +
               sRed[1024 + t + 768];
    atomicAdd(&gsum[t], a);
    atomicAdd(&gsum2[t], a2);
  }
}

// ---------------------------------------------------------------------------
// K3: per-channel BN scale/shift from accumulated sums.
// ---------------------------------------------------------------------------
__global__ void k_stats(float* __restrict__ ws, const float* __restrict__ gamma,
                        const float* __restrict__ beta) {
  int t = threadIdx.x;
  float s  = ws[WS_SUM + t];
  float s2 = ws[WS_SUMSQ + t];
  float mean = s * (1.f / 16384.f);
  float var  = fmaf(s2, 1.f / 16384.f, -mean * mean);  // biased variance
  float rstd = rsqrtf(var + 1e-5f);
  float sc = gamma[t] * rstd;
  ws[WS_SCALE + t] = sc;
  ws[WS_SHIFT + t] = fmaf(-mean, sc, beta[t]);
}

// ---------------------------------------------------------------------------
// K4: apply BN + ReLU, vectorized float4.
// ---------------------------------------------------------------------------
__global__ void k_bnrelu(const float* __restrict__ ws, float* __restrict__ out) {
  const float4* y4 = (const float4*)(ws + WS_Y);
  const float* scale = ws + WS_SCALE;
  const float* shift = ws + WS_SHIFT;
  float4* o4 = (float4*)out;
  const int n4 = BB * PP * (HH * WW / 4);  // 1048576
  for (int i = blockIdx.x * blockDim.x + threadIdx.x; i < n4;
       i += gridDim.x * blockDim.x) {
    int oc = (i >> 10) & 255;
    float sc = scale[oc], sh = shift[oc];
    float4 v = y4[i];
    float4 r;
    r.x = fmaxf(fmaf(v.x, sc, sh), 0.f);
    r.y = fmaxf(fmaf(v.y, sc, sh), 0.f);
    r.z = fmaxf(fmaf(v.z, sc, sh), 0.f);
    r.w = fmaxf(fmaf(v.w, sc, sh), 0.f);
    o4[i] = r;
  }
}

extern "C" void kernel_launch(void* const* d_in, const int* in_sizes, int n_in,
                              void* d_out, int out_size, void* d_ws,
                              size_t ws_size, hipStream_t stream) {
  const float* x     = (const float*)d_in[0];
  const float* w_p   = (const float*)d_in[1];
  const float* b_p   = (const float*)d_in[2];
  const float* w_m   = (const float*)d_in[3];
  const float* b_m   = (const float*)d_in[4];
  const float* w     = (const float*)d_in[5];
  const float* gamma = (const float*)d_in[6];
  const float* beta  = (const float*)d_in[7];
  float* ws  = (float*)d_ws;
  float* out = (float*)d_out;

  k_transpose<<<2304, 256, 0, stream>>>(w, w_p, w_m, ws);
  k_offmask<<<256, 512, 0, stream>>>(x, b_p, b_m, ws);
  k_deform<<<256, 1024, 0, stream>>>(x, ws);
  k_stats<<<1, 256, 0, stream>>>(ws, gamma, beta);
  k_bnrelu<<<2048, 256, 0, stream>>>(ws, out);
}

// Round 2
// 342.371 us; speedup vs baseline: 1.7135x; 1.7135x over previous
//
#include <hip/hip_runtime.h>
#include <math.h>

// Problem constants (fixed by the reference setup_inputs)
#define BB 4
#define CC 256
#define HH 64
#define WW 64
#define PP 256
#define NPT 9
#define NPIX 16384  // B*H*W
#define XSTR 296    // LDS x_off tile row stride (288 K + 8 pad, 16B-aligned, 2-way bank)

// Workspace layout (float element offsets)
#define WS_OFF   0ull        // [B][27][H][W]  = 442368
#define WS_Y     442368ull   // [B][P][H][W]   = 4194304
#define WS_SUM   4636672ull  // [256]
#define WS_SUMSQ 4636928ull  // [256]
#define WS_SCALE 4637184ull  // [256]
#define WS_SHIFT 4637440ull  // [256]
#define WS_WPMT  4637696ull  // [c][j][27] fp32 = 62208
#define WS_WF    4699904ull  // bf16 W fragments [ksg72][ot16][quad4][ocin16][j8] = 589824 ushort
// total ~4.99M floats = 20.0 MB

typedef __attribute__((ext_vector_type(8))) short bf16x8;
typedef __attribute__((ext_vector_type(4))) float f32x4;

static __device__ inline unsigned short f2bf(float f) {
  unsigned int u = __float_as_uint(f);
  unsigned int r = (u + 0x7FFFu + ((u >> 16) & 1u)) >> 16;
  return (unsigned short)r;
}

// ---------------------------------------------------------------------------
// K0: weight relayouts (re-done every call; ws re-poisoned before each launch).
//  - main weight -> bf16 MFMA A-fragment order [ksg][ot][quad][ocin][j]
//  - offset+mask conv weights fused -> [c][j][27]
// ---------------------------------------------------------------------------
__global__ void k_transpose(const float* __restrict__ w,
                            const float* __restrict__ w_p,
                            const float* __restrict__ w_m,
                            float* __restrict__ ws) {
  float* wPMt = ws + WS_WPMT;
  unsigned short* wfb = (unsigned short*)(ws + WS_WF);
  int idx = blockIdx.x * 256 + threadIdx.x;

  // main weight: [oc][c][k] -> fragment order; K = c*9+k = ksg*32+quad*8+j
  for (int e = idx; e < 256 * 256 * 9; e += gridDim.x * 256) {
    int j    = e & 7;
    int ocin = (e >> 3) & 15;
    int quad = (e >> 7) & 3;
    int ot   = (e >> 9) & 15;
    int ksg  = e >> 13;
    int K  = ksg * 32 + quad * 8 + j;
    int oc = ot * 16 + ocin;
    int c  = K / 9;
    int k  = K - c * 9;
    wfb[e] = f2bf(w[((size_t)oc * CC + c) * 9 + k]);
  }
  // offset+mask weights fused: [c][j][oc27]
  for (int i = idx; i < 256 * 9 * 27; i += gridDim.x * 256) {
    int oc = i % 27;
    int r  = i / 27;
    int j  = r % 9;
    int c  = r / 9;
    wPMt[i] = (oc < 18) ? w_p[((size_t)oc * CC + c) * 9 + j]
                        : w_m[((size_t)(oc - 18) * CC + c) * 9 + j];
  }
}

// ---------------------------------------------------------------------------
// K1: fused offset (18ch) + mask (9ch, sigmoid) 3x3 conv, padding=1.
// ---------------------------------------------------------------------------
__global__ __launch_bounds__(512) void k_offmask(const float* __restrict__ x,
                                                 const float* __restrict__ b_p,
                                                 const float* __restrict__ b_m,
                                                 float* __restrict__ ws) {
  const float* wPMt = ws + WS_WPMT;
  float* offm = ws + WS_OFF;

  __shared__ float sAcc[27 * 512];

  int t = threadIdx.x;
  int w = t & 63;
  int chunk = __builtin_amdgcn_readfirstlane(t >> 6);
  int blk = blockIdx.x;
  int b = blk >> 6, h = blk & 63;

  float acc[27];
#pragma unroll
  for (int j = 0; j < 27; ++j) acc[j] = 0.f;

  const float* xb = x + (size_t)b * CC * HH * WW;

  for (int ci = 0; ci < 32; ++ci) {
    int c = chunk * 32 + ci;
    const float* xp = xb + (size_t)c * HH * WW;
    float xv[9];
#pragma unroll
    for (int dh = -1; dh <= 1; ++dh) {
#pragma unroll
      for (int dw = -1; dw <= 1; ++dw) {
        int hh = h + dh, wv = w + dw;
        float v = 0.f;
        if ((unsigned)hh < 64u && (unsigned)wv < 64u) v = xp[hh * 64 + wv];
        xv[(dh + 1) * 3 + (dw + 1)] = v;
      }
    }
    const float* wb = wPMt + (size_t)c * 9 * 27;
#pragma unroll
    for (int j = 0; j < 9; ++j) {
#pragma unroll
      for (int oc = 0; oc < 27; ++oc)
        acc[oc] = fmaf(xv[j], wb[j * 27 + oc], acc[oc]);
    }
  }

#pragma unroll
  for (int j = 0; j < 27; ++j) sAcc[j * 512 + t] = acc[j];
  __syncthreads();

  for (int oi = t; oi < 27 * 64; oi += 512) {
    int oc = oi >> 6, wv = oi & 63;
    float s = 0.f;
#pragma unroll
    for (int ch = 0; ch < 8; ++ch) s += sAcc[oc * 512 + ch * 64 + wv];
    s += (oc < 18) ? b_p[oc] : b_m[oc - 18];
    if (oc >= 18) s = 1.f / (1.f + expf(-s));
    offm[(((size_t)b * 27 + oc) * 64 + h) * 64 + wv] = s;
  }
}

// ---------------------------------------------------------------------------
// K2: deformable gather + bf16 MFMA contraction.
// grid = B*H (256 blocks), block = 1024 (16 waves).
// Phase A: per (px,k) tap addresses (OOB folded into weight=0) -> LDS.
// K-block loop (32 ch): stage x_off bf16 [64 px][288 K] -> LDS, then 9
// MFMA K-steps; wave = (px-tile = wv&3, oc-group = wv>>2 covering 4 oc-tiles).
// ---------------------------------------------------------------------------
__global__ __launch_bounds__(1024) void k_deform(const float* __restrict__ x,
                                                 float* __restrict__ ws) {
  const float* offm = ws + WS_OFF;
  const unsigned short* wfb = (const unsigned short*)(ws + WS_WF);
  float* y = ws + WS_Y;

  __shared__ __align__(16) int4   sA4[576];         // 4 tap addrs (flat, safe)
  __shared__ __align__(16) float4 sG4[576];         // 4 tap weights * mask
  __shared__ __align__(16) unsigned short sXu[64 * XSTR];

  int t = threadIdx.x;
  int blk = blockIdx.x;
  int b = blk >> 6, h = blk & 63;

  if (t < 576) {
    int k = t / 64, w = t & 63;
    size_t base = (((size_t)b * 27) * 64 + h) * 64 + w;
    float offx = offm[base + (size_t)k * 4096];
    float offy = offm[base + (size_t)(9 + k) * 4096];
    float mk   = offm[base + (size_t)(18 + k) * 4096];
    float pnx = (float)((k / 3 - 1) * 6);
    float pny = (float)((k % 3 - 1) * 6);
    float px = (float)(h + 1) + pnx + offx;
    float py = (float)(w + 1) + pny + offy;
    float fx = floorf(px), fy = floorf(py);
    float q0x = fminf(fmaxf(fx, 0.f), 75.f);
    float q1x = fminf(fmaxf(fx + 1.f, 0.f), 75.f);
    float q0y = fminf(fmaxf(fy, 0.f), 75.f);
    float q1y = fminf(fmaxf(fy + 1.f, 0.f), 75.f);
    float pxc = fminf(fmaxf(px, 0.f), 75.f);
    float pyc = fminf(fmaxf(py, 0.f), 75.f);
    float glt = (1.f + (q0x - pxc)) * (1.f + (q0y - pyc));
    float grb = (1.f - (q1x - pxc)) * (1.f - (q1y - pyc));
    float glb = (1.f + (q0x - pxc)) * (1.f - (q1y - pyc));
    float grt = (1.f - (q1x - pxc)) * (1.f + (q0y - pyc));
    int ix0 = (int)q0x - 6, ix1 = (int)q1x - 6;
    int iy0 = (int)q0y - 6, iy1 = (int)q1y - 6;
    bool v00 = (unsigned)ix0 < 64u && (unsigned)iy0 < 64u;
    bool v11 = (unsigned)ix1 < 64u && (unsigned)iy1 < 64u;
    bool v01 = (unsigned)ix0 < 64u && (unsigned)iy1 < 64u;
    bool v10 = (unsigned)ix1 < 64u && (unsigned)iy0 < 64u;
    int4 a;
    a.x = v00 ? ix0 * 64 + iy0 : 0;
    a.y = v11 ? ix1 * 64 + iy1 : 0;
    a.z = v01 ? ix0 * 64 + iy1 : 0;
    a.w = v10 ? ix1 * 64 + iy0 : 0;
    float4 g;
    g.x = v00 ? glt * mk : 0.f;
    g.y = v11 ? grb * mk : 0.f;
    g.z = v01 ? glb * mk : 0.f;
    g.w = v10 ? grt * mk : 0.f;
    sA4[t] = a;
    sG4[t] = g;
  }

  int lane = t & 63;
  int wv = __builtin_amdgcn_readfirstlane(t >> 6);
  int pxt = wv & 3;        // pixel tile 0..3
  int og  = wv >> 2;       // oc-tile group 0..3 (tiles og*4 .. og*4+3)

  f32x4 acc[4];
#pragma unroll
  for (int i = 0; i < 4; ++i) acc[i] = (f32x4){0.f, 0.f, 0.f, 0.f};

  const float* xb = x + (size_t)b * CC * 4096;
  const unsigned short* bbase =
      &sXu[(pxt * 16 + (lane & 15)) * XSTR + (lane >> 4) * 8];

  for (int kb = 0; kb < 8; ++kb) {
    int c0 = kb * 32;
    __syncthreads();  // protect sXu against previous iteration's readers
    // stage 32ch x 9pt x 64px bf16 values
    for (int v = t; v < 288 * 64; v += 1024) {
      int kk = v >> 6;          // 0..287 (local K index = (c-c0)*9 + k)
      int px = v & 63;
      int cd = kk / 9;
      int k  = kk - cd * 9;
      int r  = k * 64 + px;
      const float* xp = xb + (size_t)(c0 + cd) * 4096;
      int4 a = sA4[r];
      float4 g = sG4[r];
      float val = g.x * xp[a.x];
      val = fmaf(g.y, xp[a.y], val);
      val = fmaf(g.z, xp[a.z], val);
      val = fmaf(g.w, xp[a.w], val);
      sXu[px * XSTR + kk] = f2bf(val);
    }
    __syncthreads();
#pragma unroll
    for (int ks = 0; ks < 9; ++ks) {
      bf16x8 bf = *(const bf16x8*)(bbase + ks * 32);
      int ksg = kb * 9 + ks;
      const unsigned short* ap = wfb + (size_t)ksg * 8192 + og * 4 * 512 + lane * 8;
#pragma unroll
      for (int ot4 = 0; ot4 < 4; ++ot4) {
        bf16x8 af = *(const bf16x8*)(ap + ot4 * 512);
        acc[ot4] = __builtin_amdgcn_mfma_f32_16x16x32_bf16(af, bf, acc[ot4], 0, 0, 0);
      }
    }
  }

  // epilogue: D[oc][px]; oc = (og*4+ot)*16 + (lane>>4)*4 + r, px = pxt*16+(lane&15)
  int px = pxt * 16 + (lane & 15);
  size_t ybase = (size_t)b * PP * 4096 + h * 64 + px;
#pragma unroll
  for (int ot4 = 0; ot4 < 4; ++ot4) {
#pragma unroll
    for (int r = 0; r < 4; ++r) {
      int oc = (og * 4 + ot4) * 16 + (lane >> 4) * 4 + r;
      y[ybase + (size_t)oc * 4096] = acc[ot4][r];
    }
  }
}

// ---------------------------------------------------------------------------
// K2b: per-channel sums over y (no atomics; block = one channel).
// ---------------------------------------------------------------------------
__global__ __launch_bounds__(256) void k_ysum(float* __restrict__ ws) {
  const float* y = ws + WS_Y;
  __shared__ float sR[256], sR2[256];
  int oc = blockIdx.x, t = threadIdx.x;
  float s = 0.f, s2 = 0.f;
#pragma unroll
  for (int b = 0; b < 4; ++b) {
    const float4* yp = (const float4*)(y + ((size_t)b * 256 + oc) * 4096);
    for (int i = t; i < 1024; i += 256) {
      float4 v = yp[i];
      s += v.x + v.y + v.z + v.w;
      s2 = fmaf(v.x, v.x, s2);
      s2 = fmaf(v.y, v.y, s2);
      s2 = fmaf(v.z, v.z, s2);
      s2 = fmaf(v.w, v.w, s2);
    }
  }
  sR[t] = s;
  sR2[t] = s2;
  __syncthreads();
  for (int off = 128; off > 0; off >>= 1) {
    if (t < off) {
      sR[t] += sR[t + off];
      sR2[t] += sR2[t + off];
    }
    __syncthreads();
  }
  if (t == 0) {
    ws[WS_SUM + oc] = sR[0];
    ws[WS_SUMSQ + oc] = sR2[0];
  }
}

// ---------------------------------------------------------------------------
// K3: per-channel BN scale/shift.
// ---------------------------------------------------------------------------
__global__ void k_stats(float* __restrict__ ws, const float* __restrict__ gamma,
                        const float* __restrict__ beta) {
  int t = threadIdx.x;
  float s  = ws[WS_SUM + t];
  float s2 = ws[WS_SUMSQ + t];
  float mean = s * (1.f / 16384.f);
  float var  = fmaf(s2, 1.f / 16384.f, -mean * mean);
  float rstd = rsqrtf(var + 1e-5f);
  float sc = gamma[t] * rstd;
  ws[WS_SCALE + t] = sc;
  ws[WS_SHIFT + t] = fmaf(-mean, sc, beta[t]);
}

// ---------------------------------------------------------------------------
// K4: apply BN + ReLU, vectorized float4.
// ---------------------------------------------------------------------------
__global__ void k_bnrelu(const float* __restrict__ ws, float* __restrict__ out) {
  const float4* y4 = (const float4*)(ws + WS_Y);
  const float* scale = ws + WS_SCALE;
  const float* shift = ws + WS_SHIFT;
  float4* o4 = (float4*)out;
  const int n4 = BB * PP * (HH * WW / 4);
  for (int i = blockIdx.x * blockDim.x + threadIdx.x; i < n4;
       i += gridDim.x * blockDim.x) {
    int oc = (i >> 10) & 255;
    float sc = scale[oc], sh = shift[oc];
    float4 v = y4[i];
    float4 r;
    r.x = fmaxf(fmaf(v.x, sc, sh), 0.f);
    r.y = fmaxf(fmaf(v.y, sc, sh), 0.f);
    r.z = fmaxf(fmaf(v.z, sc, sh), 0.f);
    r.w = fmaxf(fmaf(v.w, sc, sh), 0.f);
    o4[i] = r;
  }
}

extern "C" void kernel_launch(void* const* d_in, const int* in_sizes, int n_in,
                              void* d_out, int out_size, void* d_ws,
                              size_t ws_size, hipStream_t stream) {
  const float* x     = (const float*)d_in[0];
  const float* w_p   = (const float*)d_in[1];
  const float* b_p   = (const float*)d_in[2];
  const float* w_m   = (const float*)d_in[3];
  const float* b_m   = (const float*)d_in[4];
  const float* w     = (const float*)d_in[5];
  const float* gamma = (const float*)d_in[6];
  const float* beta  = (const float*)d_in[7];
  float* ws  = (float*)d_ws;
  float* out = (float*)d_out;

  k_transpose<<<2304, 256, 0, stream>>>(w, w_p, w_m, ws);
  k_offmask<<<256, 512, 0, stream>>>(x, b_p, b_m, ws);
  k_deform<<<256, 1024, 0, stream>>>(x, ws);
  k_ysum<<<256, 256, 0, stream>>>(ws);
  k_stats<<<1, 256, 0, stream>>>(ws, gamma, beta);
  k_bnrelu<<<2048, 256, 0, stream>>>(ws, out);
}